// Round 4
// baseline (73.016 us; speedup 1.0000x reference)
//
#include <hip/hip_runtime.h>
#include <hip/hip_bf16.h>

// AdaGuidedFilter: x:(4,64,256,256) f32 -> out same shape.
// out = x * (A*x + (1-A)*mean), A = var/(var+eps),
// mean/var from 11x11 zero-padded box sums normalized by in-window count.
//
// R4: 16 KB LDS (8-row vsum half-buffer, two passes) -> 8 blocks/CU cap (32 waves).
//     Interior fast paths (no bounds, one rcp per thread) for 14/16 strips and
//     30/32 column segments. Sliding windows both axes. XOR-swizzled LDS.

#define RAD    5
#define KW     11
#define IMG_H  256
#define IMG_W  256
#define TILE_H 16
#define HALF_H 8
#define IN_H   (TILE_H + 2 * RAD)   // 26
#define STRIPS (IMG_H / TILE_H)     // 16
#define EPS_F  0.01f

__device__ __forceinline__ void half_pass(const float2* __restrict__ vsum,
                                          float* __restrict__ oim,
                                          const float* xv,
                                          int lr, int seg, int c0, int gr) {
    const int rlo = (gr - RAD < 0) ? 0 : gr - RAD;
    const int rhi = (gr + RAD > IMG_H - 1) ? IMG_H - 1 : gr + RAD;
    const float rcnt = (float)(rhi - rlo + 1);

    float o[8];
    if (seg >= 1 && seg <= 30) {
        // interior: no column bounds anywhere, window count is constant 11
        float s = 0.0f, s2 = 0.0f;
        #pragma unroll
        for (int dd = -RAD; dd <= RAD; ++dd) {
            const float2 v = vsum[(lr << 8) | ((c0 + dd) ^ lr)];
            s += v.x; s2 += v.y;
        }
        const float inv = __builtin_amdgcn_rcpf(rcnt * 11.0f);
        #pragma unroll
        for (int i = 0; i < 8; ++i) {
            const float mean = s * inv;
            const float m2   = s2 * inv;
            const float var  = fmaf(-mean, mean, m2);
            const float A    = var * __builtin_amdgcn_rcpf(var + EPS_F);
            const float xq   = xv[i];
            o[i] = xq * fmaf(A, xq - mean, mean);
            if (i < 7) {
                const float2 va = vsum[(lr << 8) | ((c0 + i + RAD + 1) ^ lr)];
                const float2 vb = vsum[(lr << 8) | ((c0 + i - RAD) ^ lr)];
                s  += va.x - vb.x;
                s2 += va.y - vb.y;
            }
        }
    } else {
        // edge segments: bounds-checked reads + per-pixel window count
        float s = 0.0f, s2 = 0.0f;
        #pragma unroll
        for (int dd = -RAD; dd <= RAD; ++dd) {
            const int cc = c0 + dd;
            if (cc >= 0 && cc < IMG_W) {
                const float2 v = vsum[(lr << 8) | (cc ^ lr)];
                s += v.x; s2 += v.y;
            }
        }
        #pragma unroll
        for (int i = 0; i < 8; ++i) {
            const int c   = c0 + i;
            const int wlo = (c - RAD < 0) ? 0 : c - RAD;
            const int whi = (c + RAD > IMG_W - 1) ? IMG_W - 1 : c + RAD;
            const float inv  = __builtin_amdgcn_rcpf(rcnt * (float)(whi - wlo + 1));
            const float mean = s * inv;
            const float m2   = s2 * inv;
            const float var  = fmaf(-mean, mean, m2);
            const float A    = var * __builtin_amdgcn_rcpf(var + EPS_F);
            const float xq   = xv[i];
            o[i] = xq * fmaf(A, xq - mean, mean);
            if (i < 7) {
                const int ca = c + RAD + 1;
                const int cs = c - RAD;
                if (ca < IMG_W) { const float2 v = vsum[(lr << 8) | (ca ^ lr)]; s += v.x; s2 += v.y; }
                if (cs >= 0)    { const float2 v = vsum[(lr << 8) | (cs ^ lr)]; s -= v.x; s2 -= v.y; }
            }
        }
    }

    float4* orow = reinterpret_cast<float4*>(oim + (size_t)gr * IMG_W + c0);
    orow[0] = make_float4(o[0], o[1], o[2], o[3]);
    orow[1] = make_float4(o[4], o[5], o[6], o[7]);
}

__global__ __launch_bounds__(256, 8)
void AdaGuidedFilter_17686675325295_kernel(const float* __restrict__ x,
                                           float* __restrict__ out) {
    __shared__ float2 vsum[HALF_H * IMG_W];   // 16384 B -> 8 blocks/CU (wave cap)

    // XCD-chunked swizzle (4096 % 8 == 0 -> bijective)
    const int d     = blockIdx.x;
    const int L     = (d & 7) * ((256 * STRIPS) / 8) + (d >> 3);
    const int img   = L >> 4;
    const int strip = L & (STRIPS - 1);
    const int tid   = threadIdx.x;

    const float* __restrict__ xim = x   + (size_t)img * (IMG_H * IMG_W);
    float* __restrict__       oim = out + (size_t)img * (IMG_H * IMG_W);

    const int lr  = tid & 7;     // local row within half
    const int seg = tid >> 3;    // 0..31, 8 columns each
    const int c0  = seg * 8;
    const int grA = strip * TILE_H + lr;
    const int grB = grA + HALF_H;

    // prefetch epilogue x for half A (coalesced 128B runs per 8 lanes)
    float xvA[8];
    {
        const float4* p = reinterpret_cast<const float4*>(xim + (size_t)grA * IMG_W + c0);
        const float4 q0 = p[0], q1 = p[1];
        xvA[0]=q0.x; xvA[1]=q0.y; xvA[2]=q0.z; xvA[3]=q0.w;
        xvA[4]=q1.x; xvA[5]=q1.y; xvA[6]=q1.z; xvA[7]=q1.w;
    }

    // ---- phase 1: load 26-row column strip, vertical sliding sums ----
    float xr[IN_H];
    const int row0 = strip * TILE_H - RAD;
    if (strip != 0 && strip != STRIPS - 1) {
        #pragma unroll
        for (int li = 0; li < IN_H; ++li)
            xr[li] = xim[(size_t)(row0 + li) * IMG_W + tid];
    } else {
        #pragma unroll
        for (int li = 0; li < IN_H; ++li) {
            const int g = row0 + li;
            xr[li] = (g >= 0 && g < IMG_H) ? xim[(size_t)g * IMG_W + tid] : 0.0f;
        }
    }

    float s = 0.0f, s2 = 0.0f;
    #pragma unroll
    for (int li = 0; li < KW; ++li) { s += xr[li]; s2 = fmaf(xr[li], xr[li], s2); }

    // P1a: vsum rows 0..7 (slide after each write; exits holding row-8 window)
    #pragma unroll
    for (int r = 0; r < HALF_H; ++r) {
        vsum[(r << 8) | (tid ^ r)] = make_float2(s, s2);
        const float a = xr[r + KW], b0 = xr[r];
        s  += a - b0;
        s2 += a * a - b0 * b0;
    }
    __syncthreads();

    // P2a on rows 0..7
    half_pass(vsum, oim, xvA, lr, seg, c0, grA);
    __syncthreads();

    // prefetch half-B epilogue x (hides under P1b + barrier)
    float xvB[8];
    {
        const float4* p = reinterpret_cast<const float4*>(xim + (size_t)grB * IMG_W + c0);
        const float4 q0 = p[0], q1 = p[1];
        xvB[0]=q0.x; xvB[1]=q0.y; xvB[2]=q0.z; xvB[3]=q0.w;
        xvB[4]=q1.x; xvB[5]=q1.y; xvB[6]=q1.z; xvB[7]=q1.w;
    }

    // P1b: vsum rows 8..15 into the same half-buffer
    #pragma unroll
    for (int r = 0; r < HALF_H; ++r) {
        vsum[(r << 8) | (tid ^ r)] = make_float2(s, s2);
        if (r < HALF_H - 1) {
            const float a = xr[r + HALF_H + KW], b0 = xr[r + HALF_H];
            s  += a - b0;
            s2 += a * a - b0 * b0;
        }
    }
    __syncthreads();

    // P2b on rows 8..15
    half_pass(vsum, oim, xvB, lr, seg, c0, grB);
}

extern "C" void kernel_launch(void* const* d_in, const int* in_sizes, int n_in,
                              void* d_out, int out_size, void* d_ws, size_t ws_size,
                              hipStream_t stream) {
    (void)in_sizes; (void)n_in; (void)d_ws; (void)ws_size; (void)out_size;
    const float* x = (const float*)d_in[0];
    float* out = (float*)d_out;
    dim3 grid(256 * STRIPS);   // 4096 blocks
    dim3 block(256);
    AdaGuidedFilter_17686675325295_kernel<<<grid, block, 0, stream>>>(x, out);
}

// Round 5
// 46.485 us; speedup vs baseline: 1.5708x; 1.5708x over previous
//
#include <hip/hip_runtime.h>
#include <hip/hip_bf16.h>

// AdaGuidedFilter: x:(4,64,256,256) f32 -> out same shape.
// out = x * (A*x + (1-A)*mean), A = var/(var+eps),
// mean/var from 11x11 zero-padded box sums normalized by in-window count.
//
// R5: 16 KB LDS (8-row vsum half-buffer, two passes) for 8 blocks/CU, with a
// ring-11 vertical accumulator so the live VGPR set stays ~28 (R4 spilled:
// VGPR=32 forced, +230 MB scratch traffic). Sliding windows both axes,
// XOR-swizzled LDS, interior fast paths.

#define RAD    5
#define KW     11
#define IMG_H  256
#define IMG_W  256
#define TILE_H 16
#define HALF_H 8
#define STRIPS (IMG_H / TILE_H)     // 16
#define EPS_F  0.01f

__device__ __forceinline__ float ldrow(const float* __restrict__ xim, int g, int c) {
    // g is block-uniform -> scalar branch, no divergence
    return (g >= 0 && g < IMG_H) ? xim[(size_t)g * IMG_W + c] : 0.0f;
}

__device__ __forceinline__ void half_pass(const float2* __restrict__ vsum,
                                          const float* __restrict__ xim,
                                          float* __restrict__ oim,
                                          int lr, int seg, int c0, int gr) {
    // epilogue x: issue loads first, consume after the LDS gather
    float xv[8];
    {
        const float4* p = reinterpret_cast<const float4*>(xim + (size_t)gr * IMG_W + c0);
        const float4 q0 = p[0], q1 = p[1];
        xv[0]=q0.x; xv[1]=q0.y; xv[2]=q0.z; xv[3]=q0.w;
        xv[4]=q1.x; xv[5]=q1.y; xv[6]=q1.z; xv[7]=q1.w;
    }

    const int rlo = (gr - RAD < 0) ? 0 : gr - RAD;
    const int rhi = (gr + RAD > IMG_H - 1) ? IMG_H - 1 : gr + RAD;
    const float rcnt = (float)(rhi - rlo + 1);

    float o[8];
    if (seg >= 1 && seg <= 30) {
        float s = 0.0f, s2 = 0.0f;
        #pragma unroll
        for (int dd = -RAD; dd <= RAD; ++dd) {
            const float2 v = vsum[(lr << 8) | ((c0 + dd) ^ lr)];
            s += v.x; s2 += v.y;
        }
        const float inv = __builtin_amdgcn_rcpf(rcnt * 11.0f);
        #pragma unroll
        for (int i = 0; i < 8; ++i) {
            const float mean = s * inv;
            const float m2   = s2 * inv;
            const float var  = fmaf(-mean, mean, m2);
            const float A    = var * __builtin_amdgcn_rcpf(var + EPS_F);
            const float xq   = xv[i];
            o[i] = xq * fmaf(A, xq - mean, mean);
            if (i < 7) {
                const float2 va = vsum[(lr << 8) | ((c0 + i + RAD + 1) ^ lr)];
                const float2 vb = vsum[(lr << 8) | ((c0 + i - RAD) ^ lr)];
                s  += va.x - vb.x;
                s2 += va.y - vb.y;
            }
        }
    } else {
        float s = 0.0f, s2 = 0.0f;
        #pragma unroll
        for (int dd = -RAD; dd <= RAD; ++dd) {
            const int cc = c0 + dd;
            if (cc >= 0 && cc < IMG_W) {
                const float2 v = vsum[(lr << 8) | (cc ^ lr)];
                s += v.x; s2 += v.y;
            }
        }
        #pragma unroll
        for (int i = 0; i < 8; ++i) {
            const int c   = c0 + i;
            const int wlo = (c - RAD < 0) ? 0 : c - RAD;
            const int whi = (c + RAD > IMG_W - 1) ? IMG_W - 1 : c + RAD;
            const float inv  = __builtin_amdgcn_rcpf(rcnt * (float)(whi - wlo + 1));
            const float mean = s * inv;
            const float m2   = s2 * inv;
            const float var  = fmaf(-mean, mean, m2);
            const float A    = var * __builtin_amdgcn_rcpf(var + EPS_F);
            const float xq   = xv[i];
            o[i] = xq * fmaf(A, xq - mean, mean);
            if (i < 7) {
                const int ca = c + RAD + 1;
                const int cs = c - RAD;
                if (ca < IMG_W) { const float2 v = vsum[(lr << 8) | (ca ^ lr)]; s += v.x; s2 += v.y; }
                if (cs >= 0)    { const float2 v = vsum[(lr << 8) | (cs ^ lr)]; s -= v.x; s2 -= v.y; }
            }
        }
    }

    float4* orow = reinterpret_cast<float4*>(oim + (size_t)gr * IMG_W + c0);
    orow[0] = make_float4(o[0], o[1], o[2], o[3]);
    orow[1] = make_float4(o[4], o[5], o[6], o[7]);
}

__global__ __launch_bounds__(256, 8)
void AdaGuidedFilter_17686675325295_kernel(const float* __restrict__ x,
                                           float* __restrict__ out) {
    __shared__ float2 vsum[HALF_H * IMG_W];   // 16384 B -> 8 blocks/CU

    // XCD-chunked swizzle (4096 % 8 == 0 -> bijective)
    const int d     = blockIdx.x;
    const int L     = (d & 7) * ((256 * STRIPS) / 8) + (d >> 3);
    const int img   = L >> 4;
    const int strip = L & (STRIPS - 1);
    const int tid   = threadIdx.x;

    const float* __restrict__ xim = x   + (size_t)img * (IMG_H * IMG_W);
    float* __restrict__       oim = out + (size_t)img * (IMG_H * IMG_W);

    const int lr  = tid & 7;     // phase-2 local row
    const int seg = tid >> 3;    // phase-2 column segment (8 cols)
    const int c0  = seg * 8;
    const int grA = strip * TILE_H + lr;
    const int row0 = strip * TILE_H - RAD;

    // ---- phase 1: ring-11 vertical sliding sums (live set ~ 11+2 regs) ----
    float ring[KW];
    #pragma unroll
    for (int li = 0; li < KW; ++li) ring[li] = ldrow(xim, row0 + li, tid);

    float s = 0.0f, s2 = 0.0f;
    #pragma unroll
    for (int li = 0; li < KW; ++li) { s += ring[li]; s2 = fmaf(ring[li], ring[li], s2); }

    // P1a: vsum rows 0..7; slide after each (8 slides, loads rows row0+11..+18)
    #pragma unroll
    for (int r = 0; r < HALF_H; ++r) {
        vsum[(r << 8) | (tid ^ r)] = make_float2(s, s2);
        const int idx = r % KW;
        const float old = ring[idx];
        const float a = ldrow(xim, row0 + KW + r, tid);
        s  += a - old;
        s2 += a * a - old * old;
        ring[idx] = a;
    }
    __syncthreads();

    half_pass(vsum, xim, oim, lr, seg, c0, grA);
    __syncthreads();

    // P1b: vsum rows 8..15 (7 slides, loads rows row0+19..+25)
    #pragma unroll
    for (int r = 0; r < HALF_H; ++r) {
        vsum[(r << 8) | (tid ^ r)] = make_float2(s, s2);
        if (r < HALF_H - 1) {
            const int idx = (HALF_H + r) % KW;
            const float old = ring[idx];
            const float a = ldrow(xim, row0 + KW + HALF_H + r, tid);
            s  += a - old;
            s2 += a * a - old * old;
            ring[idx] = a;
        }
    }
    __syncthreads();

    half_pass(vsum, xim, oim, lr, seg, c0, grA + HALF_H);
}

extern "C" void kernel_launch(void* const* d_in, const int* in_sizes, int n_in,
                              void* d_out, int out_size, void* d_ws, size_t ws_size,
                              hipStream_t stream) {
    (void)in_sizes; (void)n_in; (void)d_ws; (void)ws_size; (void)out_size;
    const float* x = (const float*)d_in[0];
    float* out = (float*)d_out;
    dim3 grid(256 * STRIPS);   // 4096 blocks
    dim3 block(256);
    AdaGuidedFilter_17686675325295_kernel<<<grid, block, 0, stream>>>(x, out);
}

// Round 6
// 29.131 us; speedup vs baseline: 2.5065x; 1.5957x over previous
//
#include <hip/hip_runtime.h>
#include <hip/hip_bf16.h>

// AdaGuidedFilter: x:(4,64,256,256) f32 -> out same shape.
// out = x * (A*x + (1-A)*mean), A = var/(var+eps),
// mean/var from 11x11 zero-padded box sums normalized by in-window count.
//
// R6: TILE_H=8 single-pass blocks (grid 8192). 18-row register strip ->
// vertical sliding sums -> 16 KB XOR-swizzled LDS -> one barrier ->
// horizontal sliding window + epilogue. No forced launch-bounds min-waves
// (R4/R5's (256,8) clamped VGPR to 32 and spilled ~55-230 MB to scratch).

#define RAD    5
#define KW     11
#define IMG_H  256
#define IMG_W  256
#define TILE_H 8
#define IN_H   (TILE_H + 2 * RAD)   // 18
#define STRIPS (IMG_H / TILE_H)     // 32
#define EPS_F  0.01f

__global__ __launch_bounds__(256)
void AdaGuidedFilter_17686675325295_kernel(const float* __restrict__ x,
                                           float* __restrict__ out) {
    __shared__ float2 vsum[TILE_H * IMG_W];   // 16384 B -> LDS cap 10 blocks/CU

    // XCD-chunked swizzle (8192 % 8 == 0 -> bijective): consecutive logical
    // blocks (same image's strips) share an XCD's L2 for halo rows.
    const int d     = blockIdx.x;
    const int L     = (d & 7) * ((256 * STRIPS) / 8) + (d >> 3);
    const int img   = L >> 5;            // 0..255
    const int strip = L & (STRIPS - 1);  // 0..31
    const int tid   = threadIdx.x;

    const float* __restrict__ xim = x   + (size_t)img * (IMG_H * IMG_W);
    float* __restrict__       oim = out + (size_t)img * (IMG_H * IMG_W);

    const int row0 = strip * TILE_H - RAD;

    // ---- phase 1: vertical 11-row sliding sums, thread per column ----
    {
        float xr[IN_H];
        if (strip != 0 && strip != STRIPS - 1) {
            #pragma unroll
            for (int li = 0; li < IN_H; ++li)
                xr[li] = xim[(size_t)(row0 + li) * IMG_W + tid];
        } else {
            #pragma unroll
            for (int li = 0; li < IN_H; ++li) {
                const int g = row0 + li;
                xr[li] = (g >= 0 && g < IMG_H) ? xim[(size_t)g * IMG_W + tid] : 0.0f;
            }
        }

        float s = 0.0f, s2 = 0.0f;
        #pragma unroll
        for (int li = 0; li < KW; ++li) { s += xr[li]; s2 = fmaf(xr[li], xr[li], s2); }

        #pragma unroll
        for (int r = 0; r < TILE_H; ++r) {
            vsum[(r << 8) | (tid ^ r)] = make_float2(s, s2);
            if (r < TILE_H - 1) {
                const float a = xr[r + KW], b0 = xr[r];
                s  += a - b0;
                s2 += a * a - b0 * b0;
            }
        }
    }
    __syncthreads();

    // ---- phase 2: horizontal sliding window + epilogue ----
    const int lr  = tid & 7;     // local row
    const int seg = tid >> 3;    // 0..31, 8 columns each
    const int c0  = seg * 8;
    const int gr  = strip * TILE_H + lr;

    // epilogue x (L1/L2-resident after phase 1), issued before LDS gather
    float xv[8];
    {
        const float4* p = reinterpret_cast<const float4*>(xim + (size_t)gr * IMG_W + c0);
        const float4 q0 = p[0], q1 = p[1];
        xv[0]=q0.x; xv[1]=q0.y; xv[2]=q0.z; xv[3]=q0.w;
        xv[4]=q1.x; xv[5]=q1.y; xv[6]=q1.z; xv[7]=q1.w;
    }

    const int rlo = (gr - RAD < 0) ? 0 : gr - RAD;
    const int rhi = (gr + RAD > IMG_H - 1) ? IMG_H - 1 : gr + RAD;
    const float rcnt = (float)(rhi - rlo + 1);

    float o[8];
    if (seg >= 1 && seg <= 30) {
        // interior: no column bounds, window width constant 11 -> one rcp
        float s = 0.0f, s2 = 0.0f;
        #pragma unroll
        for (int dd = -RAD; dd <= RAD; ++dd) {
            const float2 v = vsum[(lr << 8) | ((c0 + dd) ^ lr)];
            s += v.x; s2 += v.y;
        }
        const float inv = __builtin_amdgcn_rcpf(rcnt * 11.0f);
        #pragma unroll
        for (int i = 0; i < 8; ++i) {
            const float mean = s * inv;
            const float m2   = s2 * inv;
            const float var  = fmaf(-mean, mean, m2);
            const float A    = var * __builtin_amdgcn_rcpf(var + EPS_F);
            const float xq   = xv[i];
            o[i] = xq * fmaf(A, xq - mean, mean);
            if (i < 7) {
                const float2 va = vsum[(lr << 8) | ((c0 + i + RAD + 1) ^ lr)];
                const float2 vb = vsum[(lr << 8) | ((c0 + i - RAD) ^ lr)];
                s  += va.x - vb.x;
                s2 += va.y - vb.y;
            }
        }
    } else {
        float s = 0.0f, s2 = 0.0f;
        #pragma unroll
        for (int dd = -RAD; dd <= RAD; ++dd) {
            const int cc = c0 + dd;
            if (cc >= 0 && cc < IMG_W) {
                const float2 v = vsum[(lr << 8) | (cc ^ lr)];
                s += v.x; s2 += v.y;
            }
        }
        #pragma unroll
        for (int i = 0; i < 8; ++i) {
            const int c   = c0 + i;
            const int wlo = (c - RAD < 0) ? 0 : c - RAD;
            const int whi = (c + RAD > IMG_W - 1) ? IMG_W - 1 : c + RAD;
            const float inv  = __builtin_amdgcn_rcpf(rcnt * (float)(whi - wlo + 1));
            const float mean = s * inv;
            const float m2   = s2 * inv;
            const float var  = fmaf(-mean, mean, m2);
            const float A    = var * __builtin_amdgcn_rcpf(var + EPS_F);
            const float xq   = xv[i];
            o[i] = xq * fmaf(A, xq - mean, mean);
            if (i < 7) {
                const int ca = c + RAD + 1;
                const int cs = c - RAD;
                if (ca < IMG_W) { const float2 v = vsum[(lr << 8) | (ca ^ lr)]; s += v.x; s2 += v.y; }
                if (cs >= 0)    { const float2 v = vsum[(lr << 8) | (cs ^ lr)]; s -= v.x; s2 -= v.y; }
            }
        }
    }

    float4* orow = reinterpret_cast<float4*>(oim + (size_t)gr * IMG_W + c0);
    orow[0] = make_float4(o[0], o[1], o[2], o[3]);
    orow[1] = make_float4(o[4], o[5], o[6], o[7]);
}

extern "C" void kernel_launch(void* const* d_in, const int* in_sizes, int n_in,
                              void* d_out, int out_size, void* d_ws, size_t ws_size,
                              hipStream_t stream) {
    (void)in_sizes; (void)n_in; (void)d_ws; (void)ws_size; (void)out_size;
    const float* x = (const float*)d_in[0];
    float* out = (float*)d_out;
    dim3 grid(256 * STRIPS);   // 8192 blocks
    dim3 block(256);
    AdaGuidedFilter_17686675325295_kernel<<<grid, block, 0, stream>>>(x, out);
}